// Round 1
// baseline (437.372 us; speedup 1.0000x reference)
//
#include <hip/hip_runtime.h>

// out[b][o] = sum_k x[b][k] * W[o][k] + bias[o]
// M=16 (batch), K=8192, N=8192, fp32. HBM-bound on W (256 MB).

#define B_DIM 16
#define K_DIM 8192
#define N_DIM 8192
#define BK    512                 // k-chunk staged in LDS (16x512 fp32 = 32 KB)
#define BN    16                  // output rows per workgroup
#define NTHREADS 256
#define R     4                   // output rows per wave (4 waves * 4 = 16)
#define NCHUNK (K_DIM / BK)       // 16

__global__ __launch_bounds__(NTHREADS, 2)
void qlin_gemm(const float* __restrict__ x, const float* __restrict__ w,
               const float* __restrict__ bias, float* __restrict__ out) {
    __shared__ float xs[B_DIM * BK];   // 32 KB, [b][k] row-major

    const int tid  = threadIdx.x;
    const int wid  = tid >> 6;
    const int lane = tid & 63;
    const int o0   = blockIdx.x * BN + wid * R;   // this wave's first output row

    const float* wrow0 = w + (size_t)(o0 + 0) * K_DIM;
    const float* wrow1 = w + (size_t)(o0 + 1) * K_DIM;
    const float* wrow2 = w + (size_t)(o0 + 2) * K_DIM;
    const float* wrow3 = w + (size_t)(o0 + 3) * K_DIM;

    float acc[R][B_DIM];
#pragma unroll
    for (int r = 0; r < R; ++r)
#pragma unroll
        for (int b = 0; b < B_DIM; ++b) acc[r][b] = 0.f;

    // x prefetch registers: 32 KB / 256 threads = 8 float4 per thread
    float4 xp[8];

    // ---- prologue: stage chunk 0 ----
#pragma unroll
    for (int j = 0; j < 8; ++j) {
        const int f = tid + j * NTHREADS;      // float4 index in [0, 2048)
        const int b = f >> 7;                  // f / 128
        const int k = (f & 127) << 2;          // (f % 128) * 4
        xp[j] = *reinterpret_cast<const float4*>(x + (size_t)b * K_DIM + k);
    }
#pragma unroll
    for (int j = 0; j < 8; ++j)
        reinterpret_cast<float4*>(xs)[tid + j * NTHREADS] = xp[j];
    __syncthreads();

    for (int c = 0; c < NCHUNK; ++c) {
        const int k0 = c * BK;

        // prefetch next x chunk into registers (overlaps with compute below)
        if (c + 1 < NCHUNK) {
#pragma unroll
            for (int j = 0; j < 8; ++j) {
                const int f = tid + j * NTHREADS;
                const int b = f >> 7;
                const int k = (f & 127) << 2;
                xp[j] = *reinterpret_cast<const float4*>(
                    x + (size_t)b * K_DIM + (k0 + BK) + k);
            }
        }

        // compute: 2 sub-chunks of 256 k's (lane covers k = lane*4 .. lane*4+3)
#pragma unroll
        for (int s = 0; s < 2; ++s) {
            const int kk = k0 + s * 256 + lane * 4;
            float4 wq0 = *reinterpret_cast<const float4*>(wrow0 + kk);
            float4 wq1 = *reinterpret_cast<const float4*>(wrow1 + kk);
            float4 wq2 = *reinterpret_cast<const float4*>(wrow2 + kk);
            float4 wq3 = *reinterpret_cast<const float4*>(wrow3 + kk);
#pragma unroll
            for (int b = 0; b < B_DIM; ++b) {
                const float4 xv = *reinterpret_cast<const float4*>(
                    xs + b * BK + s * 256 + lane * 4);
                acc[0][b] += wq0.x * xv.x; acc[0][b] += wq0.y * xv.y;
                acc[0][b] += wq0.z * xv.z; acc[0][b] += wq0.w * xv.w;
                acc[1][b] += wq1.x * xv.x; acc[1][b] += wq1.y * xv.y;
                acc[1][b] += wq1.z * xv.z; acc[1][b] += wq1.w * xv.w;
                acc[2][b] += wq2.x * xv.x; acc[2][b] += wq2.y * xv.y;
                acc[2][b] += wq2.z * xv.z; acc[2][b] += wq2.w * xv.w;
                acc[3][b] += wq3.x * xv.x; acc[3][b] += wq3.y * xv.y;
                acc[3][b] += wq3.z * xv.z; acc[3][b] += wq3.w * xv.w;
            }
        }

        __syncthreads();                 // everyone done reading xs chunk c
        if (c + 1 < NCHUNK) {
#pragma unroll
            for (int j = 0; j < 8; ++j)
                reinterpret_cast<float4*>(xs)[tid + j * NTHREADS] = xp[j];
        }
        __syncthreads();                 // chunk c+1 visible
    }

    // ---- epilogue: butterfly-reduce each acc over the 64 lanes ----
#pragma unroll
    for (int r = 0; r < R; ++r) {
#pragma unroll
        for (int b = 0; b < B_DIM; ++b) {
            float v = acc[r][b];
#pragma unroll
            for (int m = 32; m >= 1; m >>= 1)
                v += __shfl_xor(v, m, 64);
            acc[r][b] = v;
        }
    }

    // lane (r*16 + b) writes out[b][o0 + r]
#pragma unroll
    for (int r = 0; r < R; ++r) {
#pragma unroll
        for (int b = 0; b < B_DIM; ++b) {
            if (lane == r * 16 + b) {
                out[(size_t)b * N_DIM + (o0 + r)] = acc[r][b] + bias[o0 + r];
            }
        }
    }
}

extern "C" void kernel_launch(void* const* d_in, const int* in_sizes, int n_in,
                              void* d_out, int out_size, void* d_ws, size_t ws_size,
                              hipStream_t stream) {
    const float* x    = (const float*)d_in[0];   // [16, 8192]
    const float* w    = (const float*)d_in[1];   // [8192, 8192]
    const float* bias = (const float*)d_in[2];   // [8192]
    // d_in[3] = alpha (unused in forward)
    float* out = (float*)d_out;                  // [16, 8192]

    dim3 grid(N_DIM / BN);                       // 512 workgroups
    qlin_gemm<<<grid, NTHREADS, 0, stream>>>(x, w, bias, out);
}

// Round 2
// 374.700 us; speedup vs baseline: 1.1673x; 1.1673x over previous
//
#include <hip/hip_runtime.h>
#include <stdint.h>

// out[b][o] = sum_k x[b][k] * W[o][k] + bias[o]
// M=16, K=8192, N=8192 fp32. HBM-bound on W stream (256 MiB).
// Structure: BN=8 rows/WG (R=2/wave), BK=256 k-chunk double-buffered in LDS
// via global_load_lds (no staging VGPRs -> no spills), W float4 prefetch.

#define B_DIM 16
#define K_DIM 8192
#define N_DIM 8192
#define BK    256
#define BN    8
#define NTHREADS 256
#define NCHUNK (K_DIM / BK)   // 32

typedef const __attribute__((address_space(1))) float gfloat_t;
typedef __attribute__((address_space(3))) float lfloat_t;

__global__ __launch_bounds__(NTHREADS, 4)
void qlin_gemm(const float* __restrict__ x, const float* __restrict__ w,
               const float* __restrict__ bias, float* __restrict__ out) {
    __shared__ float xs[2][B_DIM * BK];   // 2 x 16 KB

    const int tid  = threadIdx.x;
    const int wid  = tid >> 6;
    const int lane = tid & 63;
    const int o0   = blockIdx.x * BN + wid * 2;   // this wave's 2 output rows

    const float* wrow0 = w + (size_t)o0 * K_DIM;
    const float* wrow1 = wrow0 + K_DIM;

    float acc0[B_DIM], acc1[B_DIM];
#pragma unroll
    for (int b = 0; b < B_DIM; ++b) { acc0[b] = 0.f; acc1[b] = 0.f; }

    // Async-stage x chunk c into xs[buf]. 16 KB = 1024 float4; thread tid
    // handles float4 index f = tid + j*256. Layout xs[b][kk] is linear in f,
    // so LDS dest = base + lane*16 (wave-uniform base) as global_load_lds
    // requires; global src is per-lane contiguous.
    auto stage = [&](int buf, int c) {
#pragma unroll
        for (int j = 0; j < 4; ++j) {
            const int b = wid + j * 4;                     // wave-uniform
            const float* src = x + (size_t)b * K_DIM + c * BK + lane * 4;
            lfloat_t* dst = (lfloat_t*)&xs[buf][b * BK + lane * 4];
            __builtin_amdgcn_global_load_lds((gfloat_t*)src, dst, 16, 0, 0);
        }
    };

    stage(0, 0);
    float4 wq0 = *(const float4*)(wrow0 + lane * 4);   // W for chunk 0
    float4 wq1 = *(const float4*)(wrow1 + lane * 4);
    __syncthreads();   // xs[0] ready

    for (int c = 0; c < NCHUNK; ++c) {
        const int cur = c & 1;
        float4 nq0, nq1;
        if (c + 1 < NCHUNK) {
            stage(cur ^ 1, c + 1);                       // async into other buf
            const int kn = (c + 1) * BK + lane * 4;      // W prefetch, chunk c+1
            nq0 = *(const float4*)(wrow0 + kn);
            nq1 = *(const float4*)(wrow1 + kn);
        }

        const float* xb = &xs[cur][lane * 4];
#pragma unroll
        for (int b = 0; b < B_DIM; ++b) {
            const float4 xv = *(const float4*)(xb + b * BK);  // ds_read_b128
            acc0[b] = fmaf(wq0.x, xv.x, acc0[b]);
            acc0[b] = fmaf(wq0.y, xv.y, acc0[b]);
            acc0[b] = fmaf(wq0.z, xv.z, acc0[b]);
            acc0[b] = fmaf(wq0.w, xv.w, acc0[b]);
            acc1[b] = fmaf(wq1.x, xv.x, acc1[b]);
            acc1[b] = fmaf(wq1.y, xv.y, acc1[b]);
            acc1[b] = fmaf(wq1.z, xv.z, acc1[b]);
            acc1[b] = fmaf(wq1.w, xv.w, acc1[b]);
        }

        __syncthreads();   // staging of c+1 done; xs[cur] free to overwrite
        wq0 = nq0; wq1 = nq1;
    }

    // Reduce each acc over the 64 lanes (butterfly), then predicated stores
    // with compile-time register indices (no runtime-indexed reg arrays).
#pragma unroll
    for (int b = 0; b < B_DIM; ++b) {
#pragma unroll
        for (int m = 32; m >= 1; m >>= 1) {
            acc0[b] += __shfl_xor(acc0[b], m, 64);
            acc1[b] += __shfl_xor(acc1[b], m, 64);
        }
    }

#pragma unroll
    for (int b = 0; b < B_DIM; ++b) {
        if (lane == b)      out[(size_t)b * N_DIM + o0]     = acc0[b] + bias[o0];
        if (lane == 16 + b) out[(size_t)b * N_DIM + o0 + 1] = acc1[b] + bias[o0 + 1];
    }
}

extern "C" void kernel_launch(void* const* d_in, const int* in_sizes, int n_in,
                              void* d_out, int out_size, void* d_ws, size_t ws_size,
                              hipStream_t stream) {
    const float* x    = (const float*)d_in[0];   // [16, 8192]
    const float* w    = (const float*)d_in[1];   // [8192, 8192]
    const float* bias = (const float*)d_in[2];   // [8192]
    // d_in[3] = alpha (forward is a plain GEMM; alpha only affects backward)
    float* out = (float*)d_out;                  // [16, 8192]

    dim3 grid(N_DIM / BN);                       // 1024 WGs = 4/CU
    qlin_gemm<<<grid, NTHREADS, 0, stream>>>(x, w, bias, out);
}